// Round 8
// baseline (353.217 us; speedup 1.0000x reference)
//
#include <hip/hip_runtime.h>
#include <math.h>

// CRF NLL: B=512 chains, L=1024 steps, T=48 tags.
// 1 wave per chain. Lane j<48 owns state-column j.
// PROBABILITY-DOMAIN recursion: q_j = 2^(alpha_j*log2e - Cl2).
// Per step: q'_j = (sum_i q_i * E[i][j]) * ef_j,  E=exp(trans) (fp32, 48 VGPR),
// ef_j = exp(feat_t[j]) computed from the prefetch buffer OFF the critical path.
// No exp/log/max per step. Exact power-of-2 renorm every 8 steps (shift into Cl2).
// __launch_bounds__(64, 1): 1 wave/EU -> full VGPR budget; without it the
// backend capped at 48 VGPRs and Ecol lived in memory (r7: 556 cyc/step).

constexpr int Bn = 512;
constexpr int Ln = 1024;
constexpr int Tn = 48;

#define DPP_MAX(x, ctrl)                                                      \
  x = fmaxf(x, __int_as_float(__builtin_amdgcn_update_dpp(                    \
                  __float_as_int(x), __float_as_int(x), (ctrl), 0xf, 0xf, false)))

// max over all 64 lanes, broadcast via readlane (lanes 48-63 mirror lane 0)
__device__ __forceinline__ float wave_max_bcast(float x) {
  DPP_MAX(x, 0x111);  // row_shr:1
  DPP_MAX(x, 0x112);  // row_shr:2
  DPP_MAX(x, 0x114);  // row_shr:4
  DPP_MAX(x, 0x118);  // row_shr:8
  DPP_MAX(x, 0x142);  // row_bcast:15
  DPP_MAX(x, 0x143);  // row_bcast:31
  return __int_as_float(__builtin_amdgcn_readlane(__float_as_int(x), 63));
}

#define BCAST(qb, i) __int_as_float(__builtin_amdgcn_readlane((qb), (i)))

// one CRF step in prob domain: q <- (sum_i q_i * Ecol[i]) * ef
__device__ __forceinline__ void crf_step_prob(float& q, float ef,
                                              const float (&Ecol)[Tn]) {
  int qb = __float_as_int(q);
  float a0 = 0.f, a1 = 0.f, a2 = 0.f, a3 = 0.f;
  float a4 = 0.f, a5 = 0.f, a6 = 0.f, a7 = 0.f;
#pragma unroll
  for (int g = 0; g < Tn / 8; ++g) {
    const int i = 8 * g;
    a0 = fmaf(BCAST(qb, i + 0), Ecol[i + 0], a0);
    a1 = fmaf(BCAST(qb, i + 1), Ecol[i + 1], a1);
    a2 = fmaf(BCAST(qb, i + 2), Ecol[i + 2], a2);
    a3 = fmaf(BCAST(qb, i + 3), Ecol[i + 3], a3);
    a4 = fmaf(BCAST(qb, i + 4), Ecol[i + 4], a4);
    a5 = fmaf(BCAST(qb, i + 5), Ecol[i + 5], a5);
    a6 = fmaf(BCAST(qb, i + 6), Ecol[i + 6], a6);
    a7 = fmaf(BCAST(qb, i + 7), Ecol[i + 7], a7);
  }
  float s = ((a0 + a1) + (a2 + a3)) + ((a4 + a5) + (a6 + a7));
  q = s * ef;
}

// exact power-of-2 renorm: q *= 2^-e(maxq), Cl2 += e(maxq)
__device__ __forceinline__ void renorm(float& q, float& Cl2) {
  float m = wave_max_bcast(q);
  int sexp = ((__float_as_int(m) >> 23) & 0xFF) - 127;
  q *= __int_as_float((127 - sexp) << 23);
  Cl2 += (float)sexp;
}

extern "C" __global__ void __launch_bounds__(64, 1)
crf_fwd(const float* __restrict__ feats, const float* __restrict__ trans,
        const float* __restrict__ startt, const float* __restrict__ endt,
        const int* __restrict__ tags, const int* __restrict__ mask,
        float* __restrict__ out) {
  const int b = blockIdx.x;
  const int lane = threadIdx.x;
  const int* tagr = tags + b * Ln;
  const int* maskr = mask + b * Ln;
  const float* frow = feats + (size_t)b * Ln * Tn;

  const float LOG2E = 1.44269504088896340736f;
  const float LN2 = 0.69314718055994530942f;

  // ---- sequence length n = sum(mask row); mask is a prefix mask ----
  int n = 0;
#pragma unroll
  for (int k = 0; k < Ln / 64; ++k) n += maskr[lane + 64 * k];
#pragma unroll
  for (int o = 32; o > 0; o >>= 1) n += __shfl_xor(n, o, 64);
  // n wave-uniform, n >= 512 by construction

  // ---- gold score (natural-log domain, exact) ----
  float gold = 0.f;
#pragma unroll 4
  for (int k = 0; k < Ln / 64; ++k) {
    int l = lane + 64 * k;
    int tl = tagr[l];
    float c = frow[l * Tn + tl];
    if (l == 0)
      c += startt[tl];
    else
      c += trans[tagr[l - 1] * Tn + tl];
    gold += (l < n) ? c : 0.f;
  }
#pragma unroll
  for (int o = 32; o > 0; o >>= 1) gold += __shfl_xor(gold, o, 64);
  gold += endt[tagr[n - 1]];

  // ---- E column j in fp32: Ecol[i] = exp(trans[i][j]) ----
  const int j = (lane < Tn) ? lane : 0;
  float Ecol[Tn];
#pragma unroll
  for (int i = 0; i < Tn; ++i) Ecol[i] = exp2f(trans[i * Tn + j] * LOG2E);

  // ---- init: q = 2^(b0 - M0), Cl2 = M0 (log2 domain scalar) ----
  float b0 = (startt[j] + frow[j]) * LOG2E;  // lanes>=48 mirror lane 0
  float M0 = wave_max_bcast(b0);
  float q = exp2f(b0 - M0);
  float Cl2 = M0;

  // ---- 8-deep raw feats prefetch ----
  float fb[8];
#pragma unroll
  for (int k = 0; k < 8; ++k) fb[k] = frow[(1 + k) * Tn + j];

  int t0 = 1;
  for (; t0 + 8 <= n; t0 += 8) {
    renorm(q, Cl2);  // once per 8 steps; window growth bounded < 127 bits
#pragma unroll
    for (int k = 0; k < 8; ++k) {
      float ef = exp2f(fb[k] * LOG2E);  // off critical path (indep of q)
      int tp = t0 + 8 + k;
      tp = (tp < Ln) ? tp : (Ln - 1);   // clamp: harmless re-read
      fb[k] = frow[tp * Tn + j];
      crf_step_prob(q, ef, Ecol);
    }
  }
  // tail (< 8 steps): renorm again so tail window stays bounded
  renorm(q, Cl2);
#pragma unroll
  for (int k = 0; k < 8; ++k) {
    if (t0 + k < n) {
      float ef = exp2f(fb[k] * LOG2E);
      crf_step_prob(q, ef, Ecol);
    }
  }

  // ---- fwd = (Cl2 + log2(sum_j q_j * eend_j)) * ln2 ----
  float eend = exp2f(endt[j] * LOG2E);
  float e = (lane < Tn) ? q * eend : 0.f;
#pragma unroll
  for (int o = 32; o > 0; o >>= 1) e += __shfl_xor(e, o, 64);
  float fwd = (Cl2 + log2f(e)) * LN2;

  if (lane == 0) atomicAdd(out, fwd - gold);
}

extern "C" void kernel_launch(void* const* d_in, const int* in_sizes, int n_in,
                              void* d_out, int out_size, void* d_ws, size_t ws_size,
                              hipStream_t stream) {
  const float* feats = (const float*)d_in[0];
  const float* trans = (const float*)d_in[1];
  const float* startt = (const float*)d_in[2];
  const float* endt = (const float*)d_in[3];
  const int* tags = (const int*)d_in[4];
  const int* mask = (const int*)d_in[5];
  float* out = (float*)d_out;

  (void)hipMemsetAsync(out, 0, sizeof(float), stream);
  crf_fwd<<<dim3(Bn), dim3(64), 0, stream>>>(feats, trans, startt, endt, tags,
                                             mask, out);
}

// Round 9
// 331.628 us; speedup vs baseline: 1.0651x; 1.0651x over previous
//
#include <hip/hip_runtime.h>
#include <math.h>

// CRF NLL: B=512 chains, L=1024 steps, T=48 tags.
// 1 wave per chain. Lane j<48 owns state-column j.
// PROBABILITY-DOMAIN recursion: q_j = 2^(alpha_j*log2e - Cl2).
// Per step: q'_j = (sum_i q_i * E[i][j]) * ef_j,  E=exp(trans) (fp32, 48 VGPR),
// ef_j = exp(feat_t[j]) computed from the prefetch buffer OFF the critical path.
// No exp/log/max per step. Exact power-of-2 renorm every 8 steps (shift into Cl2).
// amdgpu_waves_per_eu(1,1): pin allocator to 1 wave/EU so Ecol[48] stays in
// VGPRs. r7/r8 showed VGPR_Count=48 (Ecol in scratch, ~460 stall cyc/step);
// launch_bounds(64,1) did NOT unlock the budget (min-occupancy semantics).

constexpr int Bn = 512;
constexpr int Ln = 1024;
constexpr int Tn = 48;

#define DPP_MAX(x, ctrl)                                                      \
  x = fmaxf(x, __int_as_float(__builtin_amdgcn_update_dpp(                    \
                  __float_as_int(x), __float_as_int(x), (ctrl), 0xf, 0xf, false)))

// max over all 64 lanes, broadcast via readlane (lanes 48-63 mirror lane 0)
__device__ __forceinline__ float wave_max_bcast(float x) {
  DPP_MAX(x, 0x111);  // row_shr:1
  DPP_MAX(x, 0x112);  // row_shr:2
  DPP_MAX(x, 0x114);  // row_shr:4
  DPP_MAX(x, 0x118);  // row_shr:8
  DPP_MAX(x, 0x142);  // row_bcast:15
  DPP_MAX(x, 0x143);  // row_bcast:31
  return __int_as_float(__builtin_amdgcn_readlane(__float_as_int(x), 63));
}

#define BCAST(qb, i) __int_as_float(__builtin_amdgcn_readlane((qb), (i)))

// one CRF step in prob domain: q <- (sum_i q_i * Ecol[i]) * ef
__device__ __forceinline__ void crf_step_prob(float& q, float ef,
                                              const float (&Ecol)[Tn]) {
  int qb = __float_as_int(q);
  float a0 = 0.f, a1 = 0.f, a2 = 0.f, a3 = 0.f;
  float a4 = 0.f, a5 = 0.f, a6 = 0.f, a7 = 0.f;
#pragma unroll
  for (int g = 0; g < Tn / 8; ++g) {
    const int i = 8 * g;
    a0 = fmaf(BCAST(qb, i + 0), Ecol[i + 0], a0);
    a1 = fmaf(BCAST(qb, i + 1), Ecol[i + 1], a1);
    a2 = fmaf(BCAST(qb, i + 2), Ecol[i + 2], a2);
    a3 = fmaf(BCAST(qb, i + 3), Ecol[i + 3], a3);
    a4 = fmaf(BCAST(qb, i + 4), Ecol[i + 4], a4);
    a5 = fmaf(BCAST(qb, i + 5), Ecol[i + 5], a5);
    a6 = fmaf(BCAST(qb, i + 6), Ecol[i + 6], a6);
    a7 = fmaf(BCAST(qb, i + 7), Ecol[i + 7], a7);
  }
  float s = ((a0 + a1) + (a2 + a3)) + ((a4 + a5) + (a6 + a7));
  q = s * ef;
}

// exact power-of-2 renorm: q *= 2^-e(maxq), Cl2 += e(maxq)
__device__ __forceinline__ void renorm(float& q, float& Cl2) {
  float m = wave_max_bcast(q);
  int sexp = ((__float_as_int(m) >> 23) & 0xFF) - 127;
  q *= __int_as_float((127 - sexp) << 23);
  Cl2 += (float)sexp;
}

extern "C" __global__ void __launch_bounds__(64)
    __attribute__((amdgpu_waves_per_eu(1, 1)))
crf_fwd(const float* __restrict__ feats, const float* __restrict__ trans,
        const float* __restrict__ startt, const float* __restrict__ endt,
        const int* __restrict__ tags, const int* __restrict__ mask,
        float* __restrict__ out) {
  const int b = blockIdx.x;
  const int lane = threadIdx.x;
  const int* tagr = tags + b * Ln;
  const int* maskr = mask + b * Ln;
  const float* frow = feats + (size_t)b * Ln * Tn;

  const float LOG2E = 1.44269504088896340736f;
  const float LN2 = 0.69314718055994530942f;

  // ---- sequence length n = sum(mask row); mask is a prefix mask ----
  int n = 0;
#pragma unroll
  for (int k = 0; k < Ln / 64; ++k) n += maskr[lane + 64 * k];
#pragma unroll
  for (int o = 32; o > 0; o >>= 1) n += __shfl_xor(n, o, 64);
  // n wave-uniform, n >= 512 by construction

  // ---- gold score (natural-log domain, exact) ----
  float gold = 0.f;
#pragma unroll 4
  for (int k = 0; k < Ln / 64; ++k) {
    int l = lane + 64 * k;
    int tl = tagr[l];
    float c = frow[l * Tn + tl];
    if (l == 0)
      c += startt[tl];
    else
      c += trans[tagr[l - 1] * Tn + tl];
    gold += (l < n) ? c : 0.f;
  }
#pragma unroll
  for (int o = 32; o > 0; o >>= 1) gold += __shfl_xor(gold, o, 64);
  gold += endt[tagr[n - 1]];

  // ---- E column j in fp32: Ecol[i] = exp(trans[i][j]) ----
  const int j = (lane < Tn) ? lane : 0;
  float Ecol[Tn];
#pragma unroll
  for (int i = 0; i < Tn; ++i) Ecol[i] = exp2f(trans[i * Tn + j] * LOG2E);

  // ---- init: q = 2^(b0 - M0), Cl2 = M0 (log2 domain scalar) ----
  float b0 = (startt[j] + frow[j]) * LOG2E;  // lanes>=48 mirror lane 0
  float M0 = wave_max_bcast(b0);
  float q = exp2f(b0 - M0);
  float Cl2 = M0;

  // ---- 8-deep raw feats prefetch ----
  float fb[8];
#pragma unroll
  for (int k = 0; k < 8; ++k) fb[k] = frow[(1 + k) * Tn + j];

  int t0 = 1;
  for (; t0 + 8 <= n; t0 += 8) {
    renorm(q, Cl2);  // once per 8 steps; window growth bounded < 127 bits
#pragma unroll
    for (int k = 0; k < 8; ++k) {
      float ef = exp2f(fb[k] * LOG2E);  // off critical path (indep of q)
      int tp = t0 + 8 + k;
      tp = (tp < Ln) ? tp : (Ln - 1);   // clamp: harmless re-read
      fb[k] = frow[tp * Tn + j];
      crf_step_prob(q, ef, Ecol);
    }
  }
  // tail (< 8 steps): renorm again so tail window stays bounded
  renorm(q, Cl2);
#pragma unroll
  for (int k = 0; k < 8; ++k) {
    if (t0 + k < n) {
      float ef = exp2f(fb[k] * LOG2E);
      crf_step_prob(q, ef, Ecol);
    }
  }

  // ---- fwd = (Cl2 + log2(sum_j q_j * eend_j)) * ln2 ----
  float eend = exp2f(endt[j] * LOG2E);
  float e = (lane < Tn) ? q * eend : 0.f;
#pragma unroll
  for (int o = 32; o > 0; o >>= 1) e += __shfl_xor(e, o, 64);
  float fwd = (Cl2 + log2f(e)) * LN2;

  if (lane == 0) atomicAdd(out, fwd - gold);
}

extern "C" void kernel_launch(void* const* d_in, const int* in_sizes, int n_in,
                              void* d_out, int out_size, void* d_ws, size_t ws_size,
                              hipStream_t stream) {
  const float* feats = (const float*)d_in[0];
  const float* trans = (const float*)d_in[1];
  const float* startt = (const float*)d_in[2];
  const float* endt = (const float*)d_in[3];
  const int* tags = (const int*)d_in[4];
  const int* mask = (const int*)d_in[5];
  float* out = (float*)d_out;

  (void)hipMemsetAsync(out, 0, sizeof(float), stream);
  crf_fwd<<<dim3(Bn), dim3(64), 0, stream>>>(feats, trans, startt, endt, tags,
                                             mask, out);
}